// Round 7
// baseline (1748.373 us; speedup 1.0000x reference)
//
#include <hip/hip_runtime.h>
#include <cmath>

// Mamba_TransformerEncoder on MI355X (gfx950).
// B=4, L=512, D=512, NH=8, FF=2048, NL=4, DI=1024, DS=64, DC=4, DTR=32.
// R7: gemm_sk8_kernel -- 512 threads / 8 waves splitting K 8 ways, 3-round pairwise
// LDS tree-reduce (4x 64x66 f32 buffers, 67.6KB). Routed to the latency-bound
// N<=512, K>=512 GEMMs (PV, Wo, xp, Wout, W2) which had only 1.5-4 waves/CU on sk4.
// qkv/Win/W1 stay on sk4; S-gemm and dt-gemm on the single-wave kernel. Scan as R6.

typedef __attribute__((ext_vector_type(8))) __bf16 bf16x8;
typedef __attribute__((ext_vector_type(4))) __bf16 bf16x4;
typedef __attribute__((ext_vector_type(4))) float f32x4;

#define DEV static __device__ __forceinline__

DEV float wave_sum(float x) {
#pragma unroll
  for (int o = 32; o; o >>= 1) x += __shfl_xor(x, o, 64);
  return x;
}
DEV float wave_max(float x) {
#pragma unroll
  for (int o = 32; o; o >>= 1) x = fmaxf(x, __shfl_xor(x, o, 64));
  return x;
}

// ---------------- fp32 -> bf16 convert (x4 vectorized) ----------------
__global__ void cvt_kernel(const float* __restrict__ s, __bf16* __restrict__ d, int n4) {
  int i = blockIdx.x * 256 + threadIdx.x;
  if (i < n4) {
    float4 v = ((const float4*)s)[i];
    bf16x4 r = {(__bf16)v.x, (__bf16)v.y, (__bf16)v.z, (__bf16)v.w};
    *(bf16x4*)(d + (size_t)i * 4) = r;
  }
}

// ---------------- positional encoding + bf16 cast ----------------
__global__ void pe_kernel(const float* __restrict__ src, __bf16* __restrict__ xb) {
  int idx = blockIdx.x * 256 + threadIdx.x;  // B*L*D = 1048576
  int d = idx & 511;
  int l = (idx >> 9) & 511;
  float ang = (float)l * expf((float)(d & ~1) * (-9.210340371976184f / 512.f));
  float pe = (d & 1) ? cosf(ang) : sinf(ang);
  xb[idx] = (__bf16)(src[idx] + pe);
}

// ============ shared GEMM arg struct ============
struct GemmArgs {
  const __bf16* A; const __bf16* W;
  const float* bias; const float* add;
  float* Cf; __bf16* Cb;
  long long sAzb, sAzh, sWzb, sWzh, sADzb, sADzh, sCfzb, sCfzh, sCbzb, sCbzh;
  int lda, ldw, ldad, ldcf, ldcb;
  int M, N, K, ZH;
  float alpha; int act;  // 0 none, 1 relu, 2 softplus
  int ct;
};

// ============ single-wave 64x64 GEMM (attention S; dt-gemm w/ ct) ============
__global__ __launch_bounds__(64) void gemm_kernel(GemmArgs g) {
  const int lane = threadIdx.x;
  const int m0 = blockIdx.x * 64, n0 = blockIdx.y * 64;
  const int zb = blockIdx.z / g.ZH, zh = blockIdx.z % g.ZH;
  const __bf16* A = g.A + zb * g.sAzb + zh * g.sAzh;
  const __bf16* W = g.W + zb * g.sWzb + zh * g.sWzh;
  const int fr = lane & 15;
  const int fk = (lane >> 4) * 8;
  const __bf16* pa[4]; const __bf16* pw[4];
#pragma unroll
  for (int i = 0; i < 4; ++i) {
    int ra = m0 + i * 16 + fr;
    pa[i] = A + (size_t)ra * g.lda + fk;
    int rw = n0 + i * 16 + fr; if (rw > g.N - 1) rw = g.N - 1;
    pw[i] = W + (size_t)rw * g.ldw + fk;
  }
  f32x4 acc[4][4] = {};
  for (int k0 = 0; k0 < g.K; k0 += 32) {
    bf16x8 af[4], wf[4];
#pragma unroll
    for (int i = 0; i < 4; ++i) af[i] = *(const bf16x8*)(pa[i] + k0);
#pragma unroll
    for (int j = 0; j < 4; ++j) wf[j] = *(const bf16x8*)(pw[j] + k0);
#pragma unroll
    for (int i = 0; i < 4; ++i)
#pragma unroll
      for (int j = 0; j < 4; ++j)
        acc[i][j] = __builtin_amdgcn_mfma_f32_16x16x32_bf16(af[i], wf[j], acc[i][j], 0, 0, 0);
  }
  const float* addp = g.add ? g.add + zb * g.sADzb + zh * g.sADzh : nullptr;
  float* cf = g.Cf ? g.Cf + zb * g.sCfzb + zh * g.sCfzh : nullptr;
  __bf16* cb = g.Cb ? g.Cb + zb * g.sCbzb + zh * g.sCbzh : nullptr;
  const int rbase = m0 + (lane >> 4) * 4;
#pragma unroll
  for (int i = 0; i < 4; ++i) {
#pragma unroll
    for (int j = 0; j < 4; ++j) {
      int col = n0 + j * 16 + fr;
      if (col < g.N) {
#pragma unroll
        for (int r = 0; r < 4; ++r) {
          int row = rbase + i * 16 + r;
          float v = acc[i][j][r] * g.alpha;
          if (g.bias) v += g.bias[col];
          if (addp) v += addp[(size_t)row * g.ldad + col];
          if (g.act == 1) v = fmaxf(v, 0.f);
          else if (g.act == 2) v = (v > 20.f) ? v : log1pf(expf(v));
          if (cf) {
            if (g.ct) cf[(size_t)col * g.ldcf + row] = v;
            else      cf[(size_t)row * g.ldcf + col] = v;
          }
          if (cb) cb[(size_t)row * g.ldcb + col] = (__bf16)v;
        }
      }
    }
  }
}

static void launch_gemm(hipStream_t st,
    const __bf16* A, int lda, long long sAzb, long long sAzh,
    const __bf16* W, int ldw, long long sWzb, long long sWzh,
    const float* bias,
    const float* add, int ldad, long long sADzb, long long sADzh,
    float* Cf, int ldcf, long long sCfzb, long long sCfzh,
    __bf16* Cb, int ldcb, long long sCbzb, long long sCbzh,
    int M, int N, int K, int Z, int ZH, float alpha, int act, int ct = 0) {
  GemmArgs g;
  g.A = A; g.W = W; g.bias = bias; g.add = add; g.Cf = Cf; g.Cb = Cb;
  g.sAzb = sAzb; g.sAzh = sAzh; g.sWzb = sWzb; g.sWzh = sWzh;
  g.sADzb = sADzb; g.sADzh = sADzh; g.sCfzb = sCfzb; g.sCfzh = sCfzh;
  g.sCbzb = sCbzb; g.sCbzh = sCbzh;
  g.lda = lda; g.ldw = ldw; g.ldad = ldad; g.ldcf = ldcf; g.ldcb = ldcb;
  g.M = M; g.N = N; g.K = K; g.ZH = ZH; g.alpha = alpha; g.act = act; g.ct = ct;
  dim3 grid(M / 64, (N + 63) / 64, Z);
  gemm_kernel<<<grid, 64, 0, st>>>(g);
}

// ============ split-K 4-wave 64x64 GEMM (K%128==0) ============
__global__ __launch_bounds__(256) void gemm_sk_kernel(GemmArgs g) {
  __shared__ float red[2][64 * 66];  // 33792 B
  const int tid = threadIdx.x;
  const int lane = tid & 63;
  const int wid = tid >> 6;
  const int m0 = blockIdx.x * 64, n0 = blockIdx.y * 64;
  const int zb = blockIdx.z / g.ZH, zh = blockIdx.z % g.ZH;
  const __bf16* A = g.A + zb * g.sAzb + zh * g.sAzh;
  const __bf16* W = g.W + zb * g.sWzb + zh * g.sWzh;
  const int fr = lane & 15;
  const int fk = (lane >> 4) * 8;
  const int kbase = wid * (g.K >> 2);
  const __bf16* pa[4]; const __bf16* pw[4];
#pragma unroll
  for (int i = 0; i < 4; ++i) {
    int ra = m0 + i * 16 + fr;
    pa[i] = A + (size_t)ra * g.lda + kbase + fk;
    int rw = n0 + i * 16 + fr; if (rw > g.N - 1) rw = g.N - 1;
    pw[i] = W + (size_t)rw * g.ldw + kbase + fk;
  }
  f32x4 acc[4][4] = {};
  const int kend = g.K >> 2;
  for (int k0 = 0; k0 < kend; k0 += 32) {
    bf16x8 af[4], wf[4];
#pragma unroll
    for (int i = 0; i < 4; ++i) af[i] = *(const bf16x8*)(pa[i] + k0);
#pragma unroll
    for (int j = 0; j < 4; ++j) wf[j] = *(const bf16x8*)(pw[j] + k0);
#pragma unroll
    for (int i = 0; i < 4; ++i)
#pragma unroll
      for (int j = 0; j < 4; ++j)
        acc[i][j] = __builtin_amdgcn_mfma_f32_16x16x32_bf16(af[i], wf[j], acc[i][j], 0, 0, 0);
  }
  float* buf0 = &red[0][0];
  float* buf1 = &red[1][0];
  auto store_acc = [&](float* buf) {
#pragma unroll
    for (int i = 0; i < 4; ++i)
#pragma unroll
      for (int j = 0; j < 4; ++j) {
        int rl = i * 16 + ((lane >> 4) << 2);
        int cl = j * 16 + fr;
#pragma unroll
        for (int r = 0; r < 4; ++r) buf[(rl + r) * 66 + cl] = acc[i][j][r];
      }
  };
  auto add_acc = [&](const float* buf) {
#pragma unroll
    for (int i = 0; i < 4; ++i)
#pragma unroll
      for (int j = 0; j < 4; ++j) {
        int rl = i * 16 + ((lane >> 4) << 2);
        int cl = j * 16 + fr;
#pragma unroll
        for (int r = 0; r < 4; ++r) acc[i][j][r] += buf[(rl + r) * 66 + cl];
      }
  };
  if (wid == 1) store_acc(buf0);
  if (wid == 3) store_acc(buf1);
  __syncthreads();
  if (wid == 0) add_acc(buf0);
  if (wid == 2) add_acc(buf1);
  __syncthreads();
  if (wid == 2) store_acc(buf0);
  __syncthreads();
  if (wid == 0) { add_acc(buf0); store_acc(buf0); }
  __syncthreads();
  const int rl = tid >> 2;
  const int c0l = (tid & 3) * 16;
  const int row = m0 + rl;
  const float* addp = g.add ? g.add + zb * g.sADzb + zh * g.sADzh : nullptr;
  float* cf = g.Cf ? g.Cf + zb * g.sCfzb + zh * g.sCfzh : nullptr;
  __bf16* cb = g.Cb ? g.Cb + zb * g.sCbzb + zh * g.sCbzh : nullptr;
  float v[16];
#pragma unroll
  for (int k = 0; k < 16; ++k) {
    float x = buf0[rl * 66 + c0l + k] * g.alpha;
    int col = n0 + c0l + k;
    if (col < g.N) {
      if (g.bias) x += g.bias[col];
      if (addp) x += addp[(size_t)row * g.ldad + col];
      if (g.act == 1) x = fmaxf(x, 0.f);
      else if (g.act == 2) x = (x > 20.f) ? x : log1pf(expf(x));
    }
    v[k] = x;
  }
  if (n0 + c0l + 15 < g.N) {
    if (cf) {
      float* p = cf + (size_t)row * g.ldcf + n0 + c0l;
#pragma unroll
      for (int k = 0; k < 4; ++k) *(float4*)(p + k * 4) = *(float4*)(v + k * 4);
    }
    if (cb) {
      __bf16* p = cb + (size_t)row * g.ldcb + n0 + c0l;
#pragma unroll
      for (int h = 0; h < 2; ++h) {
        bf16x8 r;
#pragma unroll
        for (int k = 0; k < 8; ++k) r[k] = (__bf16)v[h * 8 + k];
        *(bf16x8*)(p + h * 8) = r;
      }
    }
  } else {
#pragma unroll
    for (int k = 0; k < 16; ++k) {
      int col = n0 + c0l + k;
      if (col < g.N) {
        if (cf) cf[(size_t)row * g.ldcf + col] = v[k];
        if (cb) cb[(size_t)row * g.ldcb + col] = (__bf16)v[k];
      }
    }
  }
}

static void launch_gemm_sk(hipStream_t st,
    const __bf16* A, int lda, long long sAzb, long long sAzh,
    const __bf16* W, int ldw, long long sWzb, long long sWzh,
    const float* bias,
    const float* add, int ldad, long long sADzb, long long sADzh,
    float* Cf, int ldcf, long long sCfzb, long long sCfzh,
    __bf16* Cb, int ldcb, long long sCbzb, long long sCbzh,
    int M, int N, int K, int Z, int ZH, float alpha, int act) {
  GemmArgs g;
  g.A = A; g.W = W; g.bias = bias; g.add = add; g.Cf = Cf; g.Cb = Cb;
  g.sAzb = sAzb; g.sAzh = sAzh; g.sWzb = sWzb; g.sWzh = sWzh;
  g.sADzb = sADzb; g.sADzh = sADzh; g.sCfzb = sCfzb; g.sCfzh = sCfzh;
  g.sCbzb = sCbzb; g.sCbzh = sCbzh;
  g.lda = lda; g.ldw = ldw; g.ldad = ldad; g.ldcf = ldcf; g.ldcb = ldcb;
  g.M = M; g.N = N; g.K = K; g.ZH = ZH; g.alpha = alpha; g.act = act; g.ct = 0;
  dim3 grid(M / 64, (N + 63) / 64, Z);
  gemm_sk_kernel<<<grid, 256, 0, st>>>(g);
}

// ============ split-K 8-wave 64x64 GEMM (K%256==0) ============
// 512 threads; wave w covers K-slice [w*K/8,(w+1)*K/8); pairwise tree reduce
// ((w0+w1)+(w2+w3)) + ((w4+w5)+(w6+w7)) via 4 LDS buffers (67.6KB -> 2 blocks/CU).
__global__ __launch_bounds__(512, 4) void gemm_sk8_kernel(GemmArgs g) {
  __shared__ float red[4][64 * 66];  // 67584 B
  const int tid = threadIdx.x;
  const int lane = tid & 63;
  const int wid = tid >> 6;  // 0..7
  const int m0 = blockIdx.x * 64, n0 = blockIdx.y * 64;
  const int zb = blockIdx.z / g.ZH, zh = blockIdx.z % g.ZH;
  const __bf16* A = g.A + zb * g.sAzb + zh * g.sAzh;
  const __bf16* W = g.W + zb * g.sWzb + zh * g.sWzh;
  const int fr = lane & 15;
  const int fk = (lane >> 4) * 8;
  const int kbase = wid * (g.K >> 3);
  const __bf16* pa[4]; const __bf16* pw[4];
#pragma unroll
  for (int i = 0; i < 4; ++i) {
    int ra = m0 + i * 16 + fr;
    pa[i] = A + (size_t)ra * g.lda + kbase + fk;
    int rw = n0 + i * 16 + fr; if (rw > g.N - 1) rw = g.N - 1;
    pw[i] = W + (size_t)rw * g.ldw + kbase + fk;
  }
  f32x4 acc[4][4] = {};
  const int kend = g.K >> 3;
  for (int k0 = 0; k0 < kend; k0 += 32) {
    bf16x8 af[4], wf[4];
#pragma unroll
    for (int i = 0; i < 4; ++i) af[i] = *(const bf16x8*)(pa[i] + k0);
#pragma unroll
    for (int j = 0; j < 4; ++j) wf[j] = *(const bf16x8*)(pw[j] + k0);
#pragma unroll
    for (int i = 0; i < 4; ++i)
#pragma unroll
      for (int j = 0; j < 4; ++j)
        acc[i][j] = __builtin_amdgcn_mfma_f32_16x16x32_bf16(af[i], wf[j], acc[i][j], 0, 0, 0);
  }
  auto store_acc = [&](float* buf) {
#pragma unroll
    for (int i = 0; i < 4; ++i)
#pragma unroll
      for (int j = 0; j < 4; ++j) {
        int rl = i * 16 + ((lane >> 4) << 2);
        int cl = j * 16 + fr;
#pragma unroll
        for (int r = 0; r < 4; ++r) buf[(rl + r) * 66 + cl] = acc[i][j][r];
      }
  };
  auto add_acc = [&](const float* buf) {
#pragma unroll
    for (int i = 0; i < 4; ++i)
#pragma unroll
      for (int j = 0; j < 4; ++j) {
        int rl = i * 16 + ((lane >> 4) << 2);
        int cl = j * 16 + fr;
#pragma unroll
        for (int r = 0; r < 4; ++r) acc[i][j][r] += buf[(rl + r) * 66 + cl];
      }
  };
  // round 1: w1->b0, w3->b1, w5->b2, w7->b3 ; w0+=b0, w2+=b1, w4+=b2, w6+=b3
  if (wid & 1) store_acc(&red[wid >> 1][0]);
  __syncthreads();
  if (!(wid & 1)) add_acc(&red[wid >> 1][0]);
  __syncthreads();
  // round 2: w2->b0, w6->b1 ; w0+=b0, w4+=b1
  if (wid == 2) store_acc(&red[0][0]);
  if (wid == 6) store_acc(&red[1][0]);
  __syncthreads();
  if (wid == 0) add_acc(&red[0][0]);
  if (wid == 4) add_acc(&red[1][0]);
  __syncthreads();
  // round 3: w4->b0 ; w0+=b0 ; w0 stores final
  if (wid == 4) store_acc(&red[0][0]);
  __syncthreads();
  if (wid == 0) { add_acc(&red[0][0]); store_acc(&red[0][0]); }
  __syncthreads();
  // epilogue: 512 threads x 8 elements
  const float* buf0 = &red[0][0];
  const int rl = tid >> 3;
  const int c0l = (tid & 7) * 8;
  const int row = m0 + rl;
  const float* addp = g.add ? g.add + zb * g.sADzb + zh * g.sADzh : nullptr;
  float* cf = g.Cf ? g.Cf + zb * g.sCfzb + zh * g.sCfzh : nullptr;
  __bf16* cb = g.Cb ? g.Cb + zb * g.sCbzb + zh * g.sCbzh : nullptr;
  float v[8];
#pragma unroll
  for (int k = 0; k < 8; ++k) {
    float x = buf0[rl * 66 + c0l + k] * g.alpha;
    int col = n0 + c0l + k;
    if (col < g.N) {
      if (g.bias) x += g.bias[col];
      if (addp) x += addp[(size_t)row * g.ldad + col];
      if (g.act == 1) x = fmaxf(x, 0.f);
      else if (g.act == 2) x = (x > 20.f) ? x : log1pf(expf(x));
    }
    v[k] = x;
  }
  if (n0 + c0l + 7 < g.N) {
    if (cf) {
      float* p = cf + (size_t)row * g.ldcf + n0 + c0l;
      *(float4*)(p) = *(float4*)(v);
      *(float4*)(p + 4) = *(float4*)(v + 4);
    }
    if (cb) {
      bf16x8 r;
#pragma unroll
      for (int k = 0; k < 8; ++k) r[k] = (__bf16)v[k];
      *(bf16x8*)(cb + (size_t)row * g.ldcb + n0 + c0l) = r;
    }
  } else {
#pragma unroll
    for (int k = 0; k < 8; ++k) {
      int col = n0 + c0l + k;
      if (col < g.N) {
        if (cf) cf[(size_t)row * g.ldcf + col] = v[k];
        if (cb) cb[(size_t)row * g.ldcb + col] = (__bf16)v[k];
      }
    }
  }
}

static void launch_gemm_sk8(hipStream_t st,
    const __bf16* A, int lda, long long sAzb, long long sAzh,
    const __bf16* W, int ldw, long long sWzb, long long sWzh,
    const float* bias,
    const float* add, int ldad, long long sADzb, long long sADzh,
    float* Cf, int ldcf, long long sCfzb, long long sCfzh,
    __bf16* Cb, int ldcb, long long sCbzb, long long sCbzh,
    int M, int N, int K, int Z, int ZH, float alpha, int act) {
  GemmArgs g;
  g.A = A; g.W = W; g.bias = bias; g.add = add; g.Cf = Cf; g.Cb = Cb;
  g.sAzb = sAzb; g.sAzh = sAzh; g.sWzb = sWzb; g.sWzh = sWzh;
  g.sADzb = sADzb; g.sADzh = sADzh; g.sCfzb = sCfzb; g.sCfzh = sCfzh;
  g.sCbzb = sCbzb; g.sCbzh = sCbzh;
  g.lda = lda; g.ldw = ldw; g.ldad = ldad; g.ldcf = ldcf; g.ldcb = ldcb;
  g.M = M; g.N = N; g.K = K; g.ZH = ZH; g.alpha = alpha; g.act = act; g.ct = 0;
  dim3 grid(M / 64, (N + 63) / 64, Z);
  gemm_sk8_kernel<<<grid, 512, 0, st>>>(g);
}

// ---------------- V transpose: qkv[b][l][2D + h*64 + d] -> vt[bh][d][l] ----------------
__global__ __launch_bounds__(256) void transpose_v_kernel(const __bf16* __restrict__ qkv,
                                                          __bf16* __restrict__ vt) {
  int bh = blockIdx.x, b = bh >> 3, h = bh & 7;
  const __bf16* s = qkv + (size_t)b * 512 * 1536 + 1024 + h * 64;
  __bf16* dst = vt + (size_t)bh * 64 * 512;
  __shared__ __align__(16) __bf16 tile[64 * 72];
  int tid = threadIdx.x;
  for (int l0 = 0; l0 < 512; l0 += 64) {
    __syncthreads();
#pragma unroll
    for (int it = 0; it < 2; ++it) {
      int idx = tid + it * 256;
      int l = idx >> 3, dc = (idx & 7) * 8;
      *(uint4*)&tile[l * 72 + dc] = *(const uint4*)(s + (size_t)(l0 + l) * 1536 + dc);
    }
    __syncthreads();
#pragma unroll
    for (int it = 0; it < 2; ++it) {
      int idx = tid + it * 256;
      int dd = idx >> 3, lc = (idx & 7) * 8;
      __align__(16) __bf16 tmp[8];
#pragma unroll
      for (int j = 0; j < 8; ++j) tmp[j] = tile[(lc + j) * 72 + dd];
      *(uint4*)(dst + (size_t)dd * 512 + l0 + lc) = *(uint4*)tmp;
    }
  }
}

// ---------------- row softmax over 512 cols, fp32 in -> bf16 out ----------------
__global__ __launch_bounds__(256) void softmax_kernel(const float* __restrict__ S,
                                                      __bf16* __restrict__ P) {
  int row = blockIdx.x * 4 + (threadIdx.x >> 6);
  int lane = threadIdx.x & 63;
  const float* sp = S + (size_t)row * 512 + lane * 8;
  float v[8];
  *(float4*)(v) = *(const float4*)(sp);
  *(float4*)(v + 4) = *(const float4*)(sp + 4);
  float m = v[0];
#pragma unroll
  for (int k = 1; k < 8; ++k) m = fmaxf(m, v[k]);
  m = wave_max(m);
  float s = 0.f;
#pragma unroll
  for (int k = 0; k < 8; ++k) { v[k] = __expf(v[k] - m); s += v[k]; }
  s = wave_sum(s);
  float inv = 1.f / s;
  bf16x8 r;
#pragma unroll
  for (int k = 0; k < 8; ++k) r[k] = (__bf16)(v[k] * inv);
  *(bf16x8*)(P + (size_t)row * 512 + lane * 8) = r;
}

// ---------------- depthwise causal conv (DC=4) + silu, TRANSPOSED fp32 outputs ----------------
__global__ __launch_bounds__(256) void conv_silu_t_kernel(
    const float* __restrict__ xz, const float* __restrict__ cw, const float* __restrict__ cb,
    __bf16* __restrict__ xcb, float* __restrict__ uT, float* __restrict__ s1T) {
  int c0 = blockIdx.x * 64, t0 = blockIdx.y * 64, b = blockIdx.z;
  __shared__ float su[64][65];
  __shared__ float sz[64][65];
  int c = threadIdx.x & 63;
  int tr = threadIdx.x >> 6;  // 0..3
  int ch = c0 + c;
  float w0 = cw[ch * 4 + 0], w1 = cw[ch * 4 + 1], w2 = cw[ch * 4 + 2], w3 = cw[ch * 4 + 3];
  float bias = cb[ch];
#pragma unroll 4
  for (int it = 0; it < 16; ++it) {
    int tt = it * 4 + tr;
    int t = t0 + tt;
    const float* col = xz + (size_t)b * 512 * 2048 + ch;
    float acc = bias;
    if (t >= 3) {
      acc = fmaf(w0, col[(size_t)(t - 3) * 2048], acc);
      acc = fmaf(w1, col[(size_t)(t - 2) * 2048], acc);
      acc = fmaf(w2, col[(size_t)(t - 1) * 2048], acc);
    } else {
      if (t - 3 >= 0) acc = fmaf(w0, col[(size_t)(t - 3) * 2048], acc);
      if (t - 2 >= 0) acc = fmaf(w1, col[(size_t)(t - 2) * 2048], acc);
      if (t - 1 >= 0) acc = fmaf(w2, col[(size_t)(t - 1) * 2048], acc);
    }
    acc = fmaf(w3, col[(size_t)t * 2048], acc);
    float u = acc / (1.f + __expf(-acc));
    su[tt][c] = u;
    xcb[(size_t)(b * 512 + t) * 1024 + ch] = (__bf16)u;
    float zv = col[(size_t)t * 2048 + 1024];
    sz[tt][c] = zv / (1.f + __expf(-zv));
  }
  __syncthreads();
  int c2 = threadIdx.x >> 2;
  int tb = (threadIdx.x & 3) * 16;
  size_t g = (size_t)(c0 + c2) * 2048 + (size_t)b * 512 + t0 + tb;
#pragma unroll
  for (int i = 0; i < 16; ++i) {
    uT[g + i] = su[tb + i][c2];
    s1T[g + i] = sz[tb + i][c2];
  }
}

// ---------------- chunked selective scan ----------------
__global__ __launch_bounds__(256) void scan_p1_kernel(
    const float* __restrict__ dtT, const float* __restrict__ uT,
    const float* __restrict__ xdbl, const float* __restrict__ A_log,
    float* __restrict__ Aprod, float* __restrict__ hend) {
  int w = (blockIdx.x * 256 + threadIdx.x) >> 6;  // 0..32767 = (b*1024+di)*8+c
  int lane = threadIdx.x & 63;
  int c = w & 7, di = (w >> 3) & 1023, b = w >> 13;
  float aL2 = -__expf(A_log[di * 64 + lane]) * 1.4426950408889634f;  // A*log2(e)
  int t0 = c * 64;
  size_t sbase = (size_t)di * 2048 + (size_t)b * 512 + t0;
  const float* dtp = dtT + sbase;
  const float* up = uT + sbase;
  const float* bp = xdbl + ((size_t)(b * 512 + t0)) * 160 + 32 + lane;
  float h = 0.f, sdt = 0.f;
#pragma unroll 8
  for (int s = 0; s < 64; ++s) {
    float dtv = dtp[s];
    float duv = dtv * up[s];
    float Bv = bp[(size_t)s * 160];
    float dec = exp2f(dtv * aL2);
    sdt += dtv;
    h = fmaf(dec, h, duv * Bv);
  }
  size_t o = (size_t)w * 64 + lane;
  Aprod[o] = exp2f(sdt * aL2);
  hend[o] = h;
}

__global__ __launch_bounds__(256) void scan_p2_kernel(
    const float* __restrict__ Aprod, const float* __restrict__ hend,
    float* __restrict__ hstart) {
  int w = (blockIdx.x * 256 + threadIdx.x) >> 6;  // 0..4095 = b*1024+di
  int lane = threadIdx.x & 63;
  float h = 0.f;
  size_t base = (size_t)w * 8 * 64 + lane;
#pragma unroll
  for (int c = 0; c < 8; ++c) {
    size_t o = base + (size_t)c * 64;
    hstart[o] = h;
    h = fmaf(Aprod[o], h, hend[o]);
  }
}

// Phase 3: two-section LDS row-sum (R5/R6 structure).
__global__ __launch_bounds__(128) void scan_p3_kernel(
    const float* __restrict__ dtT, const float* __restrict__ uT,
    const float* __restrict__ s1T, const float* __restrict__ xdbl,
    const float* __restrict__ A_log, const float* __restrict__ Dskip,
    const float* __restrict__ hstart, __bf16* __restrict__ yT) {
  __shared__ float Q[2][32][65];  // 16640 B per 128-thread block
  int wl = threadIdx.x >> 6;
  int w = (blockIdx.x * 128 + threadIdx.x) >> 6;
  int lane = threadIdx.x & 63;
  int c = w & 7, di = (w >> 3) & 1023, b = w >> 13;
  float aL2 = -__expf(A_log[di * 64 + lane]) * 1.4426950408889634f;
  int t0 = c * 64;
  size_t sbase = (size_t)di * 2048 + (size_t)b * 512 + t0;
  const float* dtp = dtT + sbase;
  const float* up = uT + sbase;
  const float* bp = xdbl + ((size_t)(b * 512 + t0)) * 160 + 32 + lane;
  const float* cp = bp + 64;
  float h = hstart[(size_t)w * 64 + lane];
  float y = 0.f;
#pragma unroll 8
  for (int s = 0; s < 32; ++s) {
    float dtv = dtp[s];
    float duv = dtv * up[s];
    float Bv = bp[(size_t)s * 160];
    float Cv = cp[(size_t)s * 160];
    float dec = exp2f(dtv * aL2);
    h = fmaf(dec, h, duv * Bv);
    Q[wl][s][lane] = h * Cv;
  }
  if (lane < 32) {
    const float* row = &Q[wl][lane][0];
    float a0 = 0.f, a1 = 0.f, a2 = 0.f, a3 = 0.f;
#pragma unroll
    for (int k = 0; k < 64; k += 4) {
      a0 += row[k]; a1 += row[k + 1]; a2 += row[k + 2]; a3 += row[k + 3];
    }
    y = (a0 + a1) + (a2 + a3);
  }
#pragma unroll 8
  for (int s = 32; s < 64; ++s) {
    float dtv = dtp[s];
    float duv = dtv * up[s];
    float Bv = bp[(size_t)s * 160];
    float Cv = cp[(size_t)s * 160];
    float dec = exp2f(dtv * aL2);
    h = fmaf(dec, h, duv * Bv);
    Q[wl][s - 32][lane] = h * Cv;
  }
  if (lane >= 32) {
    const float* row = &Q[wl][lane - 32][0];
    float a0 = 0.f, a1 = 0.f, a2 = 0.f, a3 = 0.f;
#pragma unroll
    for (int k = 0; k < 64; k += 4) {
      a0 += row[k]; a1 += row[k + 1]; a2 += row[k + 2]; a3 += row[k + 3];
    }
    y = (a0 + a1) + (a2 + a3);
  }
  float ue = up[lane];
  float s1e = s1T[sbase + lane];
  yT[sbase + lane] = (__bf16)((y + ue * Dskip[di]) * s1e);
}

// ---------------- yT [1024][2048] -> yb [2048][1024] bf16 transpose ----------------
__global__ __launch_bounds__(256) void transpose_y_kernel(const __bf16* __restrict__ src,
                                                          __bf16* __restrict__ dst) {
  int r0 = blockIdx.x * 64;   // di
  int c0 = blockIdx.y * 64;   // b*512+t
  __shared__ __align__(16) __bf16 tile[64 * 72];
  int tid = threadIdx.x;
#pragma unroll
  for (int it = 0; it < 2; ++it) {
    int idx = tid + it * 256;
    int r = idx >> 3, cc = (idx & 7) * 8;
    *(uint4*)&tile[r * 72 + cc] = *(const uint4*)(src + (size_t)(r0 + r) * 2048 + c0 + cc);
  }
  __syncthreads();
#pragma unroll
  for (int it = 0; it < 2; ++it) {
    int idx = tid + it * 256;
    int cr = idx >> 3, rc = (idx & 7) * 8;
    __align__(16) __bf16 tmp[8];
#pragma unroll
    for (int j = 0; j < 8; ++j) tmp[j] = tile[(rc + j) * 72 + cr];
    *(uint4*)(dst + (size_t)(c0 + cr) * 1024 + r0 + rc) = *(uint4*)tmp;
  }
}

// ---------------- layernorm over D=512, writes fp32 and/or bf16 ----------------
__global__ __launch_bounds__(256) void layernorm_kernel(const float* __restrict__ in,
    const float* __restrict__ g, const float* __restrict__ b,
    float* __restrict__ outf, __bf16* __restrict__ outb) {
  int row = blockIdx.x * 4 + (threadIdx.x >> 6);
  int lane = threadIdx.x & 63;
  const float* p = in + (size_t)row * 512 + lane * 8;
  float v[8];
  *(float4*)(v) = *(const float4*)(p);
  *(float4*)(v + 4) = *(const float4*)(p + 4);
  float s = 0.f;
#pragma unroll
  for (int k = 0; k < 8; ++k) s += v[k];
  float mean = wave_sum(s) * (1.f / 512.f);
  float q = 0.f;
#pragma unroll
  for (int k = 0; k < 8; ++k) { float d = v[k] - mean; q += d * d; }
  float var = wave_sum(q) * (1.f / 512.f);
  float rs = rsqrtf(var + 1e-5f);
  float gv[8], bv[8];
  *(float4*)(gv) = *(const float4*)(g + lane * 8);
  *(float4*)(gv + 4) = *(const float4*)(g + lane * 8 + 4);
  *(float4*)(bv) = *(const float4*)(b + lane * 8);
  *(float4*)(bv + 4) = *(const float4*)(b + lane * 8 + 4);
  float o[8];
#pragma unroll
  for (int k = 0; k < 8; ++k) o[k] = (v[k] - mean) * rs * gv[k] + bv[k];
  if (outf) {
    float* op = outf + (size_t)row * 512 + lane * 8;
    *(float4*)(op) = *(const float4*)(o);
    *(float4*)(op + 4) = *(const float4*)(o + 4);
  }
  if (outb) {
    bf16x8 r;
#pragma unroll
    for (int k = 0; k < 8; ++k) r[k] = (__bf16)o[k];
    *(bf16x8*)(outb + (size_t)row * 512 + lane * 8) = r;
  }
}

// =====================================================================================
extern "C" void kernel_launch(void* const* d_in, const int* in_sizes, int n_in,
                              void* d_out, int out_size, void* d_ws, size_t ws_size,
                              hipStream_t stream) {
  const float* src    = (const float*)d_in[0];
  const float* w_qkv  = (const float*)d_in[1];
  const float* b_qkv  = (const float*)d_in[2];
  const float* w_o    = (const float*)d_in[3];
  const float* b_o    = (const float*)d_in[4];
  const float* w1     = (const float*)d_in[5];
  const float* b1     = (const float*)d_in[6];
  const float* w2     = (const float*)d_in[7];
  const float* b2     = (const float*)d_in[8];
  const float* n1g    = (const float*)d_in[9];
  const float* n1b    = (const float*)d_in[10];
  const float* w_in   = (const float*)d_in[11];
  const float* conv_w = (const float*)d_in[12];
  const float* conv_b = (const float*)d_in[13];
  const float* w_xp   = (const float*)d_in[14];
  const float* w_dt   = (const float*)d_in[15];
  const float* b_dt   = (const float*)d_in[16];
  const float* A_log  = (const float*)d_in[17];
  const float* D_skip = (const float*)d_in[18];
  const float* w_out  = (const float*)d_in[19];
  const float* nfg    = (const float*)d_in[20];
  const float* nfb    = (const float*)d_in[21];
  (void)in_sizes; (void)n_in; (void)out_size; (void)ws_size;

  char* ws = (char*)d_ws;
  // bf16 weights (all layers)
  __bf16* Wqkv = (__bf16*)(ws + 0);          // 4*1536*512
  __bf16* Wo   = (__bf16*)(ws + 6291456);    // 4*512*512
  __bf16* W1   = (__bf16*)(ws + 8388608);    // 4*2048*512
  __bf16* W2   = (__bf16*)(ws + 16777216);   // 4*512*2048
  __bf16* Win  = (__bf16*)(ws + 25165824);   // 4*2048*512
  __bf16* Wxp  = (__bf16*)(ws + 33554432);   // 4*160*1024
  __bf16* Wdt  = (__bf16*)(ws + 34865152);   // 4*1024*32
  __bf16* Wout = (__bf16*)(ws + 35127296);   // 4*512*1024
  // activations
  __bf16* xb16 = (__bf16*)(ws + 39321600);   // 2048*512
  float*  xf32 = (float*)(ws + 41418752);    // 2048*512
  __bf16* qkvb = (__bf16*)(ws + 45613056);   // 2048*1536 (dead after PV gemm)
  __bf16* vt   = (__bf16*)(ws + 51904512);   // 32*64*512 (dead after PV gemm)
  __bf16* o_b  = (__bf16*)(ws + 54001664);   // 2048*512  (dead after Wo gemm)
  float*  a_f  = (float*)(ws + 56098816);    // 2048*512  (live until out_proj epilogue)
  __bf16* hb   = (__bf16*)(ws + 60293120);   // 2048*512
  float*  h2   = (float*)(ws + 62390272);    // 2048*512 fp32
  // region R1 (32MB, disjoint lifetimes)
  float*  Sf    = (float*)(ws + 66584576);
  float*  xzf   = (float*)(ws + 66584576);
  float*  dtT   = (float*)(ws + 66584576);
  float*  hend0 = (float*)(ws + 74973184);
  float*  uT    = (float*)(ws + 83361792);
  float*  s1T   = (float*)(ws + 91750400);
  // scan summaries overlaying dead regions during scan phases:
  float*  hstart = (float*)(ws + 45613056);  // over qkvb+vt (8MB), dead after PV
  __bf16* yT     = (__bf16*)(ws + 60293120); // over hb+h2[0:2MB] (4MB), dead during scan
  // region R2: P bf16 (16MB) | { xcb b16, xdbl f32/b16, y b16, ffn-mid b16 }
  __bf16* Pb    = (__bf16*)(ws + 100139008); // 32*512*512
  __bf16* xcb   = (__bf16*)(ws + 100139008);               // 2048*1024 bf16
  float*  xdblf = (float*)(ws + 100139008 + 4194304);      // 2048*160
  __bf16* xdblb = (__bf16*)(ws + 100139008 + 5505024);     // 2048*160
  __bf16* yb    = (__bf16*)(ws + 100139008 + 6160384);     // 2048*1024
  __bf16* fb    = (__bf16*)(ws + 100139008 + 10354688);    // 2048*2048 (dead during scan)
  float*  Aprod = (float*)(ws + 110493696);  // over fb (8MB exactly)
  // total = 118882304 bytes (~113.4 MB) -- unchanged

  auto cvt = [&](const float* s, __bf16* dptr, long long n) {
    int n4 = (int)(n / 4);
    cvt_kernel<<<(n4 + 255) / 256, 256, 0, stream>>>(s, dptr, n4);
  };
  cvt(w_qkv, Wqkv, 4LL * 1536 * 512);
  cvt(w_o,   Wo,   4LL * 512 * 512);
  cvt(w1,    W1,   4LL * 2048 * 512);
  cvt(w2,    W2,   4LL * 512 * 2048);
  cvt(w_in,  Win,  4LL * 2048 * 512);
  cvt(w_xp,  Wxp,  4LL * 160 * 1024);
  cvt(w_dt,  Wdt,  4LL * 1024 * 32);
  cvt(w_out, Wout, 4LL * 512 * 1024);

  pe_kernel<<<4096, 256, 0, stream>>>(src, xb16);

  for (int i = 0; i < 4; ++i) {
    // ---- attention branch ----
    launch_gemm_sk(stream, xb16, 512, 0, 0, Wqkv + (size_t)i * 1536 * 512, 512, 0, 0,
                   b_qkv + i * 1536, nullptr, 0, 0, 0,
                   nullptr, 0, 0, 0, qkvb, 1536, 0, 0,
                   2048, 1536, 512, 1, 1, 1.f, 0);
    transpose_v_kernel<<<32, 256, 0, stream>>>(qkvb, vt);
    launch_gemm(stream, qkvb, 1536, 512LL * 1536, 64, qkvb + 512, 1536, 512LL * 1536, 64,
                nullptr, nullptr, 0, 0, 0,
                Sf, 512, 2097152LL, 262144LL, nullptr, 0, 0, 0,
                512, 512, 64, 32, 8, 0.125f, 0);
    softmax_kernel<<<4096, 256, 0, stream>>>(Sf, Pb);
    launch_gemm_sk8(stream, Pb, 512, 2097152LL, 262144LL, vt, 512, 262144LL, 32768LL,
                    nullptr, nullptr, 0, 0, 0,
                    nullptr, 0, 0, 0, o_b, 512, 262144LL, 64LL,
                    512, 64, 512, 32, 8, 1.f, 0);
    launch_gemm_sk8(stream, o_b, 512, 0, 0, Wo + (size_t)i * 512 * 512, 512, 0, 0,
                    b_o + i * 512, nullptr, 0, 0, 0,
                    a_f, 512, 0, 0, nullptr, 0, 0, 0,
                    2048, 512, 512, 1, 1, 1.f, 0);
    // ---- mamba branch ----
    launch_gemm_sk(stream, xb16, 512, 0, 0, Win + (size_t)i * 2048 * 512, 512, 0, 0,
                   nullptr, nullptr, 0, 0, 0,
                   xzf, 2048, 0, 0, nullptr, 0, 0, 0,
                   2048, 2048, 512, 1, 1, 1.f, 0);
    conv_silu_t_kernel<<<dim3(16, 8, 4), 256, 0, stream>>>(
        xzf, conv_w + i * 1024 * 4, conv_b + i * 1024, xcb, uT, s1T);
    launch_gemm_sk8(stream, xcb, 1024, 0, 0, Wxp + (size_t)i * 160 * 1024, 1024, 0, 0,
                    nullptr, nullptr, 0, 0, 0,
                    xdblf, 160, 0, 0, xdblb, 160, 0, 0,
                    2048, 160, 1024, 1, 1, 1.f, 0);
    // dt = softplus(dt_in @ Wdt^T + b_dt) -> TRANSPOSED into dtT (old kernel, ct=1)
    launch_gemm(stream, xdblb, 160, 0, 0, Wdt + (size_t)i * 1024 * 32, 32, 0, 0,
                b_dt + i * 1024, nullptr, 0, 0, 0,
                dtT, 2048, 0, 0, nullptr, 0, 0, 0,
                2048, 1024, 32, 1, 1, 1.f, 2, /*ct=*/1);
    // chunked scan: 3 phases + transpose
    scan_p1_kernel<<<8192, 256, 0, stream>>>(dtT, uT, xdblf,
                                             A_log + (size_t)i * 1024 * 64, Aprod, hend0);
    scan_p2_kernel<<<1024, 256, 0, stream>>>(Aprod, hend0, hstart);
    scan_p3_kernel<<<16384, 128, 0, stream>>>(dtT, uT, s1T, xdblf,
                                              A_log + (size_t)i * 1024 * 64,
                                              D_skip + i * 1024, hstart, yT);
    transpose_y_kernel<<<dim3(16, 32), 256, 0, stream>>>(yT, yb);
    launch_gemm_sk8(stream, yb, 1024, 0, 0, Wout + (size_t)i * 512 * 1024, 1024, 0, 0,
                    nullptr, a_f, 512, 0, 0,
                    nullptr, 0, 0, 0, hb, 512, 0, 0,
                    2048, 512, 1024, 1, 1, 1.f, 0);
    // ---- FFN + LN ----
    launch_gemm_sk(stream, hb, 512, 0, 0, W1 + (size_t)i * 2048 * 512, 512, 0, 0,
                   b1 + i * 2048, nullptr, 0, 0, 0,
                   nullptr, 0, 0, 0, fb, 2048, 0, 0,
                   2048, 2048, 512, 1, 1, 1.f, 1);
    launch_gemm_sk8(stream, fb, 2048, 0, 0, W2 + (size_t)i * 512 * 2048, 2048, 0, 0,
                    b2 + i * 512, nullptr, 0, 0, 0,
                    h2, 512, 0, 0, nullptr, 0, 0, 0,
                    2048, 512, 2048, 1, 1, 1.f, 0);
    layernorm_kernel<<<512, 256, 0, stream>>>(h2, n1g + i * 512, n1b + i * 512, xf32, xb16);
  }
  // final layernorm -> d_out (fp32)
  layernorm_kernel<<<512, 256, 0, stream>>>(xf32, nfg, nfb, (float*)d_out, nullptr);
}

// Round 8
// 1654.671 us; speedup vs baseline: 1.0566x; 1.0566x over previous
//
#include <hip/hip_runtime.h>
#include <cmath>

// Mamba_TransformerEncoder on MI355X (gfx950).
// B=4, L=512, D=512, NH=8, FF=2048, NL=4, DI=1024, DS=64, DC=4, DTR=32.
// R8: (1) revert GEMM routing to R6 (all sk4; sk8 removed -- its 3rd reduce round ate
// the split gain). (2) attn_sm_kernel fuses S=QK^T/8 + softmax in-wave (16 rows/wave,
// quad-shuffle row reduce, no Sf round-trip). (3) p1/p3 dt/u stream loads -> float4.

typedef __attribute__((ext_vector_type(8))) __bf16 bf16x8;
typedef __attribute__((ext_vector_type(4))) __bf16 bf16x4;
typedef __attribute__((ext_vector_type(4))) float f32x4;

#define DEV static __device__ __forceinline__

DEV float wave_sum(float x) {
#pragma unroll
  for (int o = 32; o; o >>= 1) x += __shfl_xor(x, o, 64);
  return x;
}
DEV float wave_max(float x) {
#pragma unroll
  for (int o = 32; o; o >>= 1) x = fmaxf(x, __shfl_xor(x, o, 64));
  return x;
}

// ---------------- fp32 -> bf16 convert (x4 vectorized) ----------------
__global__ void cvt_kernel(const float* __restrict__ s, __bf16* __restrict__ d, int n4) {
  int i = blockIdx.x * 256 + threadIdx.x;
  if (i < n4) {
    float4 v = ((const float4*)s)[i];
    bf16x4 r = {(__bf16)v.x, (__bf16)v.y, (__bf16)v.z, (__bf16)v.w};
    *(bf16x4*)(d + (size_t)i * 4) = r;
  }
}

// ---------------- positional encoding + bf16 cast ----------------
__global__ void pe_kernel(const float* __restrict__ src, __bf16* __restrict__ xb) {
  int idx = blockIdx.x * 256 + threadIdx.x;  // B*L*D = 1048576
  int d = idx & 511;
  int l = (idx >> 9) & 511;
  float ang = (float)l * expf((float)(d & ~1) * (-9.210340371976184f / 512.f));
  float pe = (d & 1) ? cosf(ang) : sinf(ang);
  xb[idx] = (__bf16)(src[idx] + pe);
}

// ============ shared GEMM arg struct ============
struct GemmArgs {
  const __bf16* A; const __bf16* W;
  const float* bias; const float* add;
  float* Cf; __bf16* Cb;
  long long sAzb, sAzh, sWzb, sWzh, sADzb, sADzh, sCfzb, sCfzh, sCbzb, sCbzh;
  int lda, ldw, ldad, ldcf, ldcb;
  int M, N, K, ZH;
  float alpha; int act;  // 0 none, 1 relu, 2 softplus
  int ct;
};

// ============ single-wave 64x64 GEMM (dt-gemm w/ ct) ============
__global__ __launch_bounds__(64) void gemm_kernel(GemmArgs g) {
  const int lane = threadIdx.x;
  const int m0 = blockIdx.x * 64, n0 = blockIdx.y * 64;
  const int zb = blockIdx.z / g.ZH, zh = blockIdx.z % g.ZH;
  const __bf16* A = g.A + zb * g.sAzb + zh * g.sAzh;
  const __bf16* W = g.W + zb * g.sWzb + zh * g.sWzh;
  const int fr = lane & 15;
  const int fk = (lane >> 4) * 8;
  const __bf16* pa[4]; const __bf16* pw[4];
#pragma unroll
  for (int i = 0; i < 4; ++i) {
    int ra = m0 + i * 16 + fr;
    pa[i] = A + (size_t)ra * g.lda + fk;
    int rw = n0 + i * 16 + fr; if (rw > g.N - 1) rw = g.N - 1;
    pw[i] = W + (size_t)rw * g.ldw + fk;
  }
  f32x4 acc[4][4] = {};
  for (int k0 = 0; k0 < g.K; k0 += 32) {
    bf16x8 af[4], wf[4];
#pragma unroll
    for (int i = 0; i < 4; ++i) af[i] = *(const bf16x8*)(pa[i] + k0);
#pragma unroll
    for (int j = 0; j < 4; ++j) wf[j] = *(const bf16x8*)(pw[j] + k0);
#pragma unroll
    for (int i = 0; i < 4; ++i)
#pragma unroll
      for (int j = 0; j < 4; ++j)
        acc[i][j] = __builtin_amdgcn_mfma_f32_16x16x32_bf16(af[i], wf[j], acc[i][j], 0, 0, 0);
  }
  const float* addp = g.add ? g.add + zb * g.sADzb + zh * g.sADzh : nullptr;
  float* cf = g.Cf ? g.Cf + zb * g.sCfzb + zh * g.sCfzh : nullptr;
  __bf16* cb = g.Cb ? g.Cb + zb * g.sCbzb + zh * g.sCbzh : nullptr;
  const int rbase = m0 + (lane >> 4) * 4;
#pragma unroll
  for (int i = 0; i < 4; ++i) {
#pragma unroll
    for (int j = 0; j < 4; ++j) {
      int col = n0 + j * 16 + fr;
      if (col < g.N) {
#pragma unroll
        for (int r = 0; r < 4; ++r) {
          int row = rbase + i * 16 + r;
          float v = acc[i][j][r] * g.alpha;
          if (g.bias) v += g.bias[col];
          if (addp) v += addp[(size_t)row * g.ldad + col];
          if (g.act == 1) v = fmaxf(v, 0.f);
          else if (g.act == 2) v = (v > 20.f) ? v : log1pf(expf(v));
          if (cf) {
            if (g.ct) cf[(size_t)col * g.ldcf + row] = v;
            else      cf[(size_t)row * g.ldcf + col] = v;
          }
          if (cb) cb[(size_t)row * g.ldcb + col] = (__bf16)v;
        }
      }
    }
  }
}

static void launch_gemm(hipStream_t st,
    const __bf16* A, int lda, long long sAzb, long long sAzh,
    const __bf16* W, int ldw, long long sWzb, long long sWzh,
    const float* bias,
    const float* add, int ldad, long long sADzb, long long sADzh,
    float* Cf, int ldcf, long long sCfzb, long long sCfzh,
    __bf16* Cb, int ldcb, long long sCbzb, long long sCbzh,
    int M, int N, int K, int Z, int ZH, float alpha, int act, int ct = 0) {
  GemmArgs g;
  g.A = A; g.W = W; g.bias = bias; g.add = add; g.Cf = Cf; g.Cb = Cb;
  g.sAzb = sAzb; g.sAzh = sAzh; g.sWzb = sWzb; g.sWzh = sWzh;
  g.sADzb = sADzb; g.sADzh = sADzh; g.sCfzb = sCfzb; g.sCfzh = sCfzh;
  g.sCbzb = sCbzb; g.sCbzh = sCbzh;
  g.lda = lda; g.ldw = ldw; g.ldad = ldad; g.ldcf = ldcf; g.ldcb = ldcb;
  g.M = M; g.N = N; g.K = K; g.ZH = ZH; g.alpha = alpha; g.act = act; g.ct = ct;
  dim3 grid(M / 64, (N + 63) / 64, Z);
  gemm_kernel<<<grid, 64, 0, st>>>(g);
}

// ============ split-K 4-wave 64x64 GEMM (K%128==0) ============
__global__ __launch_bounds__(256) void gemm_sk_kernel(GemmArgs g) {
  __shared__ float red[2][64 * 66];  // 33792 B
  const int tid = threadIdx.x;
  const int lane = tid & 63;
  const int wid = tid >> 6;
  const int m0 = blockIdx.x * 64, n0 = blockIdx.y * 64;
  const int zb = blockIdx.z / g.ZH, zh = blockIdx.z % g.ZH;
  const __bf16* A = g.A + zb * g.sAzb + zh * g.sAzh;
  const __bf16* W = g.W + zb * g.sWzb + zh * g.sWzh;
  const int fr = lane & 15;
  const int fk = (lane >> 4) * 8;
  const int kbase = wid * (g.K >> 2);
  const __bf16* pa[4]; const __bf16* pw[4];
#pragma unroll
  for (int i = 0; i < 4; ++i) {
    int ra = m0 + i * 16 + fr;
    pa[i] = A + (size_t)ra * g.lda + kbase + fk;
    int rw = n0 + i * 16 + fr; if (rw > g.N - 1) rw = g.N - 1;
    pw[i] = W + (size_t)rw * g.ldw + kbase + fk;
  }
  f32x4 acc[4][4] = {};
  const int kend = g.K >> 2;
  for (int k0 = 0; k0 < kend; k0 += 32) {
    bf16x8 af[4], wf[4];
#pragma unroll
    for (int i = 0; i < 4; ++i) af[i] = *(const bf16x8*)(pa[i] + k0);
#pragma unroll
    for (int j = 0; j < 4; ++j) wf[j] = *(const bf16x8*)(pw[j] + k0);
#pragma unroll
    for (int i = 0; i < 4; ++i)
#pragma unroll
      for (int j = 0; j < 4; ++j)
        acc[i][j] = __builtin_amdgcn_mfma_f32_16x16x32_bf16(af[i], wf[j], acc[i][j], 0, 0, 0);
  }
  float* buf0 = &red[0][0];
  float* buf1 = &red[1][0];
  auto store_acc = [&](float* buf) {
#pragma unroll
    for (int i = 0; i < 4; ++i)
#pragma unroll
      for (int j = 0; j < 4; ++j) {
        int rl = i * 16 + ((lane >> 4) << 2);
        int cl = j * 16 + fr;
#pragma unroll
        for (int r = 0; r < 4; ++r) buf[(rl + r) * 66 + cl] = acc[i][j][r];
      }
  };
  auto add_acc = [&](const float* buf) {
#pragma unroll
    for (int i = 0; i < 4; ++i)
#pragma unroll
      for (int j = 0; j < 4; ++j) {
        int rl = i * 16 + ((lane >> 4) << 2);
        int cl = j * 16 + fr;
#pragma unroll
        for (int r = 0; r < 4; ++r) acc[i][j][r] += buf[(rl + r) * 66 + cl];
      }
  };
  if (wid == 1) store_acc(buf0);
  if (wid == 3) store_acc(buf1);
  __syncthreads();
  if (wid == 0) add_acc(buf0);
  if (wid == 2) add_acc(buf1);
  __syncthreads();
  if (wid == 2) store_acc(buf0);
  __syncthreads();
  if (wid == 0) { add_acc(buf0); store_acc(buf0); }
  __syncthreads();
  const int rl = tid >> 2;
  const int c0l = (tid & 3) * 16;
  const int row = m0 + rl;
  const float* addp = g.add ? g.add + zb * g.sADzb + zh * g.sADzh : nullptr;
  float* cf = g.Cf ? g.Cf + zb * g.sCfzb + zh * g.sCfzh : nullptr;
  __bf16* cb = g.Cb ? g.Cb + zb * g.sCbzb + zh * g.sCbzh : nullptr;
  float v[16];
#pragma unroll
  for (int k = 0; k < 16; ++k) {
    float x = buf0[rl * 66 + c0l + k] * g.alpha;
    int col = n0 + c0l + k;
    if (col < g.N) {
      if (g.bias) x += g.bias[col];
      if (addp) x += addp[(size_t)row * g.ldad + col];
      if (g.act == 1) x = fmaxf(x, 0.f);
      else if (g.act == 2) x = (x > 20.f) ? x : log1pf(expf(x));
    }
    v[k] = x;
  }
  if (n0 + c0l + 15 < g.N) {
    if (cf) {
      float* p = cf + (size_t)row * g.ldcf + n0 + c0l;
#pragma unroll
      for (int k = 0; k < 4; ++k) *(float4*)(p + k * 4) = *(float4*)(v + k * 4);
    }
    if (cb) {
      __bf16* p = cb + (size_t)row * g.ldcb + n0 + c0l;
#pragma unroll
      for (int h = 0; h < 2; ++h) {
        bf16x8 r;
#pragma unroll
        for (int k = 0; k < 8; ++k) r[k] = (__bf16)v[h * 8 + k];
        *(bf16x8*)(p + h * 8) = r;
      }
    }
  } else {
#pragma unroll
    for (int k = 0; k < 16; ++k) {
      int col = n0 + c0l + k;
      if (col < g.N) {
        if (cf) cf[(size_t)row * g.ldcf + col] = v[k];
        if (cb) cb[(size_t)row * g.ldcb + col] = (__bf16)v[k];
      }
    }
  }
}

static void launch_gemm_sk(hipStream_t st,
    const __bf16* A, int lda, long long sAzb, long long sAzh,
    const __bf16* W, int ldw, long long sWzb, long long sWzh,
    const float* bias,
    const float* add, int ldad, long long sADzb, long long sADzh,
    float* Cf, int ldcf, long long sCfzb, long long sCfzh,
    __bf16* Cb, int ldcb, long long sCbzb, long long sCbzh,
    int M, int N, int K, int Z, int ZH, float alpha, int act) {
  GemmArgs g;
  g.A = A; g.W = W; g.bias = bias; g.add = add; g.Cf = Cf; g.Cb = Cb;
  g.sAzb = sAzb; g.sAzh = sAzh; g.sWzb = sWzb; g.sWzh = sWzh;
  g.sADzb = sADzb; g.sADzh = sADzh; g.sCfzb = sCfzb; g.sCfzh = sCfzh;
  g.sCbzb = sCbzb; g.sCbzh = sCbzh;
  g.lda = lda; g.ldw = ldw; g.ldad = ldad; g.ldcf = ldcf; g.ldcb = ldcb;
  g.M = M; g.N = N; g.K = K; g.ZH = ZH; g.alpha = alpha; g.act = act; g.ct = 0;
  dim3 grid(M / 64, (N + 63) / 64, Z);
  gemm_sk_kernel<<<grid, 256, 0, st>>>(g);
}

// ============ fused attention scores + softmax ============
// grid (8, 32): x = 64-row block, y = (b*8+h). 4 waves/block; wave w owns 16 full rows.
// Each wave: acc[32] f32x4 = 16 rows x 512 cols of QK^T; softmax per row is reduced
// across the 16 lanes of a quad (shfl_xor 1/2/4/8 stays in-quad); writes P bf16.
__global__ __launch_bounds__(256) void attn_sm_kernel(const __bf16* __restrict__ qkv,
                                                      __bf16* __restrict__ P) {
  const int bh = blockIdx.y, b = bh >> 3, h = bh & 7;
  const int w = threadIdx.x >> 6, lane = threadIdx.x & 63;
  const int fr = lane & 15, fk = (lane >> 4) * 8;
  const __bf16* qb = qkv + (size_t)b * 512 * 1536 + h * 64;   // Q: + l*1536 + k
  const __bf16* kb = qb + 512;                                 // K
  const int arow = blockIdx.x * 64 + w * 16 + fr;              // A-frag row (m = lane&15)
  const __bf16* qp = qb + (size_t)arow * 1536 + fk;
  f32x4 acc[32];
#pragma unroll
  for (int j = 0; j < 32; ++j) acc[j] = (f32x4){0.f, 0.f, 0.f, 0.f};
#pragma unroll
  for (int kk = 0; kk < 2; ++kk) {
    bf16x8 af = *(const bf16x8*)(qp + kk * 32);
#pragma unroll
    for (int j = 0; j < 32; ++j) {
      bf16x8 wf = *(const bf16x8*)(kb + (size_t)(j * 16 + fr) * 1536 + kk * 32 + fk);
      acc[j] = __builtin_amdgcn_mfma_f32_16x16x32_bf16(af, wf, acc[j], 0, 0, 0);
    }
  }
  // output rows: blockIdx.x*64 + w*16 + (lane>>4)*4 + r ; col = j*16 + fr
  __bf16* Pb = P + (size_t)bh * 512 * 512;
  const int rbase = blockIdx.x * 64 + w * 16 + ((lane >> 4) << 2);
#pragma unroll
  for (int r = 0; r < 4; ++r) {
    float m = -1e30f;
#pragma unroll
    for (int j = 0; j < 32; ++j) m = fmaxf(m, acc[j][r]);
#pragma unroll
    for (int o = 1; o < 16; o <<= 1) m = fmaxf(m, __shfl_xor(m, o, 64));
    float s = 0.f;
#pragma unroll
    for (int j = 0; j < 32; ++j) {
      float e = __expf((acc[j][r] - m) * 0.125f);
      acc[j][r] = e;
      s += e;
    }
#pragma unroll
    for (int o = 1; o < 16; o <<= 1) s += __shfl_xor(s, o, 64);
    float inv = 1.f / s;
    __bf16* prow = Pb + (size_t)(rbase + r) * 512 + fr;
#pragma unroll
    for (int j = 0; j < 32; ++j) prow[j * 16] = (__bf16)(acc[j][r] * inv);
  }
}

// ---------------- V transpose: qkv[b][l][2D + h*64 + d] -> vt[bh][d][l] ----------------
__global__ __launch_bounds__(256) void transpose_v_kernel(const __bf16* __restrict__ qkv,
                                                          __bf16* __restrict__ vt) {
  int bh = blockIdx.x, b = bh >> 3, h = bh & 7;
  const __bf16* s = qkv + (size_t)b * 512 * 1536 + 1024 + h * 64;
  __bf16* dst = vt + (size_t)bh * 64 * 512;
  __shared__ __align__(16) __bf16 tile[64 * 72];
  int tid = threadIdx.x;
  for (int l0 = 0; l0 < 512; l0 += 64) {
    __syncthreads();
#pragma unroll
    for (int it = 0; it < 2; ++it) {
      int idx = tid + it * 256;
      int l = idx >> 3, dc = (idx & 7) * 8;
      *(uint4*)&tile[l * 72 + dc] = *(const uint4*)(s + (size_t)(l0 + l) * 1536 + dc);
    }
    __syncthreads();
#pragma unroll
    for (int it = 0; it < 2; ++it) {
      int idx = tid + it * 256;
      int dd = idx >> 3, lc = (idx & 7) * 8;
      __align__(16) __bf16 tmp[8];
#pragma unroll
      for (int j = 0; j < 8; ++j) tmp[j] = tile[(lc + j) * 72 + dd];
      *(uint4*)(dst + (size_t)dd * 512 + l0 + lc) = *(uint4*)tmp;
    }
  }
}

// ---------------- depthwise causal conv (DC=4) + silu, TRANSPOSED fp32 outputs ----------------
__global__ __launch_bounds__(256) void conv_silu_t_kernel(
    const float* __restrict__ xz, const float* __restrict__ cw, const float* __restrict__ cb,
    __bf16* __restrict__ xcb, float* __restrict__ uT, float* __restrict__ s1T) {
  int c0 = blockIdx.x * 64, t0 = blockIdx.y * 64, b = blockIdx.z;
  __shared__ float su[64][65];
  __shared__ float sz[64][65];
  int c = threadIdx.x & 63;
  int tr = threadIdx.x >> 6;  // 0..3
  int ch = c0 + c;
  float w0 = cw[ch * 4 + 0], w1 = cw[ch * 4 + 1], w2 = cw[ch * 4 + 2], w3 = cw[ch * 4 + 3];
  float bias = cb[ch];
#pragma unroll 4
  for (int it = 0; it < 16; ++it) {
    int tt = it * 4 + tr;
    int t = t0 + tt;
    const float* col = xz + (size_t)b * 512 * 2048 + ch;
    float acc = bias;
    if (t >= 3) {
      acc = fmaf(w0, col[(size_t)(t - 3) * 2048], acc);
      acc = fmaf(w1, col[(size_t)(t - 2) * 2048], acc);
      acc = fmaf(w2, col[(size_t)(t - 1) * 2048], acc);
    } else {
      if (t - 3 >= 0) acc = fmaf(w0, col[(size_t)(t - 3) * 2048], acc);
      if (t - 2 >= 0) acc = fmaf(w1, col[(size_t)(t - 2) * 2048], acc);
      if (t - 1 >= 0) acc = fmaf(w2, col[(size_t)(t - 1) * 2048], acc);
    }
    acc = fmaf(w3, col[(size_t)t * 2048], acc);
    float u = acc / (1.f + __expf(-acc));
    su[tt][c] = u;
    xcb[(size_t)(b * 512 + t) * 1024 + ch] = (__bf16)u;
    float zv = col[(size_t)t * 2048 + 1024];
    sz[tt][c] = zv / (1.f + __expf(-zv));
  }
  __syncthreads();
  int c2 = threadIdx.x >> 2;
  int tb = (threadIdx.x & 3) * 16;
  size_t g = (size_t)(c0 + c2) * 2048 + (size_t)b * 512 + t0 + tb;
#pragma unroll
  for (int i = 0; i < 16; ++i) {
    uT[g + i] = su[tb + i][c2];
    s1T[g + i] = sz[tb + i][c2];
  }
}

// ---------------- chunked selective scan ----------------
// Phase 1: h from h0=0, per-lane chunk summary. dt/u streams loaded as float4.
__global__ __launch_bounds__(256) void scan_p1_kernel(
    const float* __restrict__ dtT, const float* __restrict__ uT,
    const float* __restrict__ xdbl, const float* __restrict__ A_log,
    float* __restrict__ Aprod, float* __restrict__ hend) {
  int w = (blockIdx.x * 256 + threadIdx.x) >> 6;  // (b*1024+di)*8+c
  int lane = threadIdx.x & 63;
  int c = w & 7, di = (w >> 3) & 1023, b = w >> 13;
  float aL2 = -__expf(A_log[di * 64 + lane]) * 1.4426950408889634f;  // A*log2(e)
  int t0 = c * 64;
  size_t sbase = (size_t)di * 2048 + (size_t)b * 512 + t0;
  const float* dtp = dtT + sbase;
  const float* up = uT + sbase;
  const float* bp = xdbl + ((size_t)(b * 512 + t0)) * 160 + 32 + lane;
  float h = 0.f, sdt = 0.f;
#pragma unroll 2
  for (int s4 = 0; s4 < 64; s4 += 4) {
    float4 dt4 = *(const float4*)(dtp + s4);
    float4 u4 = *(const float4*)(up + s4);
#pragma unroll
    for (int q = 0; q < 4; ++q) {
      float dtv = ((const float*)&dt4)[q];
      float uv = ((const float*)&u4)[q];
      float Bv = bp[(size_t)(s4 + q) * 160];
      float dec = exp2f(dtv * aL2);
      sdt += dtv;
      h = fmaf(dec, h, (dtv * uv) * Bv);
    }
  }
  size_t o = (size_t)w * 64 + lane;
  Aprod[o] = exp2f(sdt * aL2);
  hend[o] = h;
}

__global__ __launch_bounds__(256) void scan_p2_kernel(
    const float* __restrict__ Aprod, const float* __restrict__ hend,
    float* __restrict__ hstart) {
  int w = (blockIdx.x * 256 + threadIdx.x) >> 6;  // b*1024+di
  int lane = threadIdx.x & 63;
  float h = 0.f;
  size_t base = (size_t)w * 8 * 64 + lane;
#pragma unroll
  for (int c = 0; c < 8; ++c) {
    size_t o = base + (size_t)c * 64;
    hstart[o] = h;
    h = fmaf(Aprod[o], h, hend[o]);
  }
}

// Phase 3: two-section LDS row-sum; dt/u streams as float4.
__global__ __launch_bounds__(128) void scan_p3_kernel(
    const float* __restrict__ dtT, const float* __restrict__ uT,
    const float* __restrict__ s1T, const float* __restrict__ xdbl,
    const float* __restrict__ A_log, const float* __restrict__ Dskip,
    const float* __restrict__ hstart, __bf16* __restrict__ yT) {
  __shared__ float Q[2][32][65];  // 16640 B per 128-thread block
  int wl = threadIdx.x >> 6;
  int w = (blockIdx.x * 128 + threadIdx.x) >> 6;
  int lane = threadIdx.x & 63;
  int c = w & 7, di = (w >> 3) & 1023, b = w >> 13;
  float aL2 = -__expf(A_log[di * 64 + lane]) * 1.4426950408889634f;
  int t0 = c * 64;
  size_t sbase = (size_t)di * 2048 + (size_t)b * 512 + t0;
  const float* dtp = dtT + sbase;
  const float* up = uT + sbase;
  const float* bp = xdbl + ((size_t)(b * 512 + t0)) * 160 + 32 + lane;
  const float* cp = bp + 64;
  float h = hstart[(size_t)w * 64 + lane];
  float y = 0.f;
#pragma unroll 2
  for (int s4 = 0; s4 < 32; s4 += 4) {
    float4 dt4 = *(const float4*)(dtp + s4);
    float4 u4 = *(const float4*)(up + s4);
#pragma unroll
    for (int q = 0; q < 4; ++q) {
      int s = s4 + q;
      float dtv = ((const float*)&dt4)[q];
      float uv = ((const float*)&u4)[q];
      float Bv = bp[(size_t)s * 160];
      float Cv = cp[(size_t)s * 160];
      float dec = exp2f(dtv * aL2);
      h = fmaf(dec, h, (dtv * uv) * Bv);
      Q[wl][s][lane] = h * Cv;
    }
  }
  if (lane < 32) {
    const float* row = &Q[wl][lane][0];
    float a0 = 0.f, a1 = 0.f, a2 = 0.f, a3 = 0.f;
#pragma unroll
    for (int k = 0; k < 64; k += 4) {
      a0 += row[k]; a1 += row[k + 1]; a2 += row[k + 2]; a3 += row[k + 3];
    }
    y = (a0 + a1) + (a2 + a3);
  }
#pragma unroll 2
  for (int s4 = 32; s4 < 64; s4 += 4) {
    float4 dt4 = *(const float4*)(dtp + s4);
    float4 u4 = *(const float4*)(up + s4);
#pragma unroll
    for (int q = 0; q < 4; ++q) {
      int s = s4 + q;
      float dtv = ((const float*)&dt4)[q];
      float uv = ((const float*)&u4)[q];
      float Bv = bp[(size_t)s * 160];
      float Cv = cp[(size_t)s * 160];
      float dec = exp2f(dtv * aL2);
      h = fmaf(dec, h, (dtv * uv) * Bv);
      Q[wl][s - 32][lane] = h * Cv;
    }
  }
  if (lane >= 32) {
    const float* row = &Q[wl][lane - 32][0];
    float a0 = 0.f, a1 = 0.f, a2 = 0.f, a3 = 0.f;
#pragma unroll
    for (int k = 0; k < 64; k += 4) {
      a0 += row[k]; a1 += row[k + 1]; a2 += row[k + 2]; a3 += row[k + 3];
    }
    y = (a0 + a1) + (a2 + a3);
  }
  float ue = up[lane];
  float s1e = s1T[sbase + lane];
  yT[sbase + lane] = (__bf16)((y + ue * Dskip[di]) * s1e);
}

// ---------------- yT [1024][2048] -> yb [2048][1024] bf16 transpose ----------------
__global__ __launch_bounds__(256) void transpose_y_kernel(const __bf16* __restrict__ src,
                                                          __bf16* __restrict__ dst) {
  int r0 = blockIdx.x * 64;   // di
  int c0 = blockIdx.y * 64;   // b*512+t
  __shared__ __align__(16) __bf16 tile[64 * 72];
  int tid = threadIdx.x;
#pragma unroll
  for (int it = 0; it < 2; ++it) {
    int idx = tid + it * 256;
    int r = idx >> 3, cc = (idx & 7) * 8;
    *(uint4*)&tile[r * 72 + cc] = *(const uint4*)(src + (size_t)(r0 + r) * 2048 + c0 + cc);
  }
  __syncthreads();
#pragma unroll
  for (int it = 0; it < 2; ++it) {
    int idx = tid + it * 256;
    int cr = idx >> 3, rc = (idx & 7) * 8;
    __align__(16) __bf16 tmp[8];
#pragma unroll
    for (int j = 0; j < 8; ++j) tmp[j] = tile[(rc + j) * 72 + cr];
    *(uint4*)(dst + (size_t)(c0 + cr) * 1024 + r0 + rc) = *(uint4*)tmp;
  }
}

// ---------------- layernorm over D=512, writes fp32 and/or bf16 ----------------
__global__ __launch_bounds__(256) void layernorm_kernel(const float* __restrict__ in,
    const float* __restrict__ g, const float* __restrict__ b,
    float* __restrict__ outf, __bf16* __restrict__ outb) {
  int row = blockIdx.x * 4 + (threadIdx.x >> 6);
  int lane = threadIdx.x & 63;
  const float* p = in + (size_t)row * 512 + lane * 8;
  float v[8];
  *(float4*)(v) = *(const float4*)(p);
  *(float4*)(v + 4) = *(const float4*)(p + 4);
  float s = 0.f;
#pragma unroll
  for (int k = 0; k < 8; ++k) s += v[k];
  float mean = wave_sum(s) * (1.f / 512.f);
  float q = 0.f;
#pragma unroll
  for (int k = 0; k < 8; ++k) { float d = v[k] - mean; q += d * d; }
  float var = wave_sum(q) * (1.f / 512.f);
  float rs = rsqrtf(var + 1e-5f);
  float gv[8], bv[8];
  *(float4*)(gv) = *(const float4*)(g + lane * 8);
  *(float4*)(gv + 4) = *(const float4*)(g + lane * 8 + 4);
  *(float4*)(bv) = *(const float4*)(b + lane * 8);
  *(float4*)(bv + 4) = *(const float4*)(b + lane * 8 + 4);
  float o[8];
#pragma unroll
  for (int k = 0; k < 8; ++k) o[k] = (v[k] - mean) * rs * gv[k] + bv[k];
  if (outf) {
    float* op = outf + (size_t)row * 512 + lane * 8;
    *(float4*)(op) = *(const float4*)(o);
    *(float4*)(op + 4) = *(const float4*)(o + 4);
  }
  if (outb) {
    bf16x8 r;
#pragma unroll
    for (int k = 0; k < 8; ++k) r[k] = (__bf16)o[k];
    *(bf16x8*)(outb + (size_t)row * 512 + lane * 8) = r;
  }
}

// =====================================================================================
extern "C" void kernel_launch(void* const* d_in, const int* in_sizes, int n_in,
                              void* d_out, int out_size, void* d_ws, size_t ws_size,
                              hipStream_t stream) {
  const float* src    = (const float*)d_in[0];
  const float* w_qkv  = (const float*)d_in[1];
  const float* b_qkv  = (const float*)d_in[2];
  const float* w_o    = (const float*)d_in[3];
  const float* b_o    = (const float*)d_in[4];
  const float* w1     = (const float*)d_in[5];
  const float* b1     = (const float*)d_in[6];
  const float* w2     = (const float*)d_in[7];
  const float* b2     = (const float*)d_in[8];
  const float* n1g    = (const float*)d_in[9];
  const float* n1b    = (const float*)d_in[10];
  const float* w_in   = (const float*)d_in[11];
  const float* conv_w = (const float*)d_in[12];
  const float* conv_b = (const float*)d_in[13];
  const float* w_xp   = (const float*)d_in[14];
  const float* w_dt   = (const float*)d_in[15];
  const float* b_dt   = (const float*)d_in[16];
  const float* A_log  = (const float*)d_in[17];
  const float* D_skip = (const float*)d_in[18];
  const float* w_out  = (const float*)d_in[19];
  const float* nfg    = (const float*)d_in[20];
  const float* nfb    = (const float*)d_in[21];
  (void)in_sizes; (void)n_in; (void)out_size; (void)ws_size;

  char* ws = (char*)d_ws;
  // bf16 weights (all layers)
  __bf16* Wqkv = (__bf16*)(ws + 0);          // 4*1536*512
  __bf16* Wo   = (__bf16*)(ws + 6291456);    // 4*512*512
  __bf16* W1   = (__bf16*)(ws + 8388608);    // 4*2048*512
  __bf16* W2   = (__bf16*)(ws + 16777216);   // 4*512*2048
  __bf16* Win  = (__bf16*)(ws + 25165824);   // 4*2048*512
  __bf16* Wxp  = (__bf16*)(ws + 33554432);   // 4*160*1024
  __bf16* Wdt  = (__bf16*)(ws + 34865152);   // 4*1024*32
  __bf16* Wout = (__bf16*)(ws + 35127296);   // 4*512*1024
  // activations
  __bf16* xb16 = (__bf16*)(ws + 39321600);   // 2048*512
  float*  xf32 = (float*)(ws + 41418752);    // 2048*512
  __bf16* qkvb = (__bf16*)(ws + 45613056);   // 2048*1536 (dead after PV gemm)
  __bf16* vt   = (__bf16*)(ws + 51904512);   // 32*64*512 (dead after PV gemm)
  __bf16* o_b  = (__bf16*)(ws + 54001664);   // 2048*512  (dead after Wo gemm)
  float*  a_f  = (float*)(ws + 56098816);    // 2048*512
  __bf16* hb   = (__bf16*)(ws + 60293120);   // 2048*512
  float*  h2   = (float*)(ws + 62390272);    // 2048*512 fp32
  // region R1 (32MB, disjoint lifetimes)
  float*  xzf   = (float*)(ws + 66584576);
  float*  dtT   = (float*)(ws + 66584576);
  float*  hend0 = (float*)(ws + 74973184);
  float*  uT    = (float*)(ws + 83361792);
  float*  s1T   = (float*)(ws + 91750400);
  // scan summaries overlaying dead regions during scan phases:
  float*  hstart = (float*)(ws + 45613056);  // over qkvb+vt (8MB), dead after PV
  __bf16* yT     = (__bf16*)(ws + 60293120); // over hb+h2[0:2MB], dead during scan
  // region R2: P bf16 (16MB) | { xcb b16, xdbl f32/b16, y b16, ffn-mid b16 }
  __bf16* Pb    = (__bf16*)(ws + 100139008); // 32*512*512
  __bf16* xcb   = (__bf16*)(ws + 100139008);               // 2048*1024 bf16
  float*  xdblf = (float*)(ws + 100139008 + 4194304);      // 2048*160
  __bf16* xdblb = (__bf16*)(ws + 100139008 + 5505024);     // 2048*160
  __bf16* yb    = (__bf16*)(ws + 100139008 + 6160384);     // 2048*1024
  __bf16* fb    = (__bf16*)(ws + 100139008 + 10354688);    // 2048*2048 (dead during scan)
  float*  Aprod = (float*)(ws + 110493696);  // over fb (8MB exactly)
  // total = 118882304 bytes (~113.4 MB) -- unchanged

  auto cvt = [&](const float* s, __bf16* dptr, long long n) {
    int n4 = (int)(n / 4);
    cvt_kernel<<<(n4 + 255) / 256, 256, 0, stream>>>(s, dptr, n4);
  };
  cvt(w_qkv, Wqkv, 4LL * 1536 * 512);
  cvt(w_o,   Wo,   4LL * 512 * 512);
  cvt(w1,    W1,   4LL * 2048 * 512);
  cvt(w2,    W2,   4LL * 512 * 2048);
  cvt(w_in,  Win,  4LL * 2048 * 512);
  cvt(w_xp,  Wxp,  4LL * 160 * 1024);
  cvt(w_dt,  Wdt,  4LL * 1024 * 32);
  cvt(w_out, Wout, 4LL * 512 * 1024);

  pe_kernel<<<4096, 256, 0, stream>>>(src, xb16);

  for (int i = 0; i < 4; ++i) {
    // ---- attention branch ----
    launch_gemm_sk(stream, xb16, 512, 0, 0, Wqkv + (size_t)i * 1536 * 512, 512, 0, 0,
                   b_qkv + i * 1536, nullptr, 0, 0, 0,
                   nullptr, 0, 0, 0, qkvb, 1536, 0, 0,
                   2048, 1536, 512, 1, 1, 1.f, 0);
    transpose_v_kernel<<<32, 256, 0, stream>>>(qkvb, vt);
    attn_sm_kernel<<<dim3(8, 32), 256, 0, stream>>>(qkvb, Pb);
    launch_gemm_sk(stream, Pb, 512, 2097152LL, 262144LL, vt, 512, 262144LL, 32768LL,
                   nullptr, nullptr, 0, 0, 0,
                   nullptr, 0, 0, 0, o_b, 512, 262144LL, 64LL,
                   512, 64, 512, 32, 8, 1.f, 0);
    launch_gemm_sk(stream, o_b, 512, 0, 0, Wo + (size_t)i * 512 * 512, 512, 0, 0,
                   b_o + i * 512, nullptr, 0, 0, 0,
                   a_f, 512, 0, 0, nullptr, 0, 0, 0,
                   2048, 512, 512, 1, 1, 1.f, 0);
    // ---- mamba branch ----
    launch_gemm_sk(stream, xb16, 512, 0, 0, Win + (size_t)i * 2048 * 512, 512, 0, 0,
                   nullptr, nullptr, 0, 0, 0,
                   xzf, 2048, 0, 0, nullptr, 0, 0, 0,
                   2048, 2048, 512, 1, 1, 1.f, 0);
    conv_silu_t_kernel<<<dim3(16, 8, 4), 256, 0, stream>>>(
        xzf, conv_w + i * 1024 * 4, conv_b + i * 1024, xcb, uT, s1T);
    launch_gemm_sk(stream, xcb, 1024, 0, 0, Wxp + (size_t)i * 160 * 1024, 1024, 0, 0,
                   nullptr, nullptr, 0, 0, 0,
                   xdblf, 160, 0, 0, xdblb, 160, 0, 0,
                   2048, 160, 1024, 1, 1, 1.f, 0);
    // dt = softplus(dt_in @ Wdt^T + b_dt) -> TRANSPOSED into dtT (ct=1)
    launch_gemm(stream, xdblb, 160, 0, 0, Wdt + (size_t)i * 1024 * 32, 32, 0, 0,
                b_dt + i * 1024, nullptr, 0, 0, 0,
                dtT, 2048, 0, 0, nullptr, 0, 0, 0,
                2048, 1024, 32, 1, 1, 1.f, 2, /*ct=*/1);
    // chunked scan: 3 phases + transpose
    scan_p1_kernel<<<8192, 256, 0, stream>>>(dtT, uT, xdblf,
                                             A_log + (size_t)i * 1024 * 64, Aprod, hend0);
    scan_p2_kernel<<<1024, 256, 0, stream>>>(Aprod, hend0, hstart);
    scan_p3_kernel<<<16384, 128, 0, stream>>>(dtT, uT, s1T, xdblf,
                                              A_log + (size_t)i * 1024 * 64,
                                              D_skip + i * 1024, hstart, yT);
    transpose_y_kernel<<<dim3(16, 32), 256, 0, stream>>>(yT, yb);
    launch_gemm_sk(stream, yb, 1024, 0, 0, Wout + (size_t)i * 512 * 1024, 1024, 0, 0,
                   nullptr, a_f, 512, 0, 0,
                   nullptr, 0, 0, 0, hb, 512, 0, 0,
                   2048, 512, 1024, 1, 1, 1.f, 0);
    // ---- FFN + LN ----
    launch_gemm_sk(stream, hb, 512, 0, 0, W1 + (size_t)i * 2048 * 512, 512, 0, 0,
                   b1 + i * 2048, nullptr, 0, 0, 0,
                   nullptr, 0, 0, 0, fb, 2048, 0, 0,
                   2048, 2048, 512, 1, 1, 1.f, 1);
    launch_gemm_sk(stream, fb, 2048, 0, 0, W2 + (size_t)i * 512 * 2048, 2048, 0, 0,
                   b2 + i * 512, nullptr, 0, 0, 0,
                   h2, 512, 0, 0, nullptr, 0, 0, 0,
                   2048, 512, 2048, 1, 1, 1.f, 0);
    layernorm_kernel<<<512, 256, 0, stream>>>(h2, n1g + i * 512, n1b + i * 512, xf32, xb16);
  }
  // final layernorm -> d_out (fp32)
  layernorm_kernel<<<512, 256, 0, stream>>>(xf32, nfg, nfb, (float*)d_out, nullptr);
}